// Round 1
// baseline (344.385 us; speedup 1.0000x reference)
//
#include <hip/hip_runtime.h>
#include <hip/hip_bf16.h>
#include <math.h>

// Problem constants
#define TS   24
#define NH   4
#define HD   128
#define D    512
#define NB   64
#define SEQ  512
#define NTOT (NB*SEQ)   // 32768

typedef __bf16 bf16;
typedef __bf16 bf16x8 __attribute__((ext_vector_type(8)));
typedef float  f32x4  __attribute__((ext_vector_type(4)));

// Workspace layout (float offsets)
#define OFF_QU  0        // [64][512]   qu[b][h*128+e]  (includes bq)
#define OFF_QT  32768    // [24][512]   qt[t][h*128+e]
#define OFF_K   45056    // [24][512]   k[kk][h*128+e]  (includes bk)
#define OFF_V   57344    // [24][512]   v[kk][h*128+e]  (includes bv)
#define OFF_SU  69632    // [64][4][24] scale*log2e * qu.k
#define OFF_ST  75776    // [24][4][24] scale*log2e * qt.k
#define OFF_BSW 78080    // bf16 region: [12 groups][544 cols][8 k] = 52224 bf16

// ---------------------------------------------------------------------------
// K1: projections. qu (32768 outputs, 512-dots), qt/k/v (3 x 12288, 512-dots).
// qu mapping: lane = b so the Wq row load is wave-uniform; up rows hit L1
// (sliding 64B window over 64 rows = 4KB working set).
// ---------------------------------------------------------------------------
__global__ __launch_bounds__(256) void k1_proj(
    const float* __restrict__ timeslot, const int* __restrict__ user_x,
    const float* __restrict__ upt,
    const float* __restrict__ Wq, const float* __restrict__ bq,
    const float* __restrict__ Wk, const float* __restrict__ bk,
    const float* __restrict__ Wv, const float* __restrict__ bv,
    float* __restrict__ ws)
{
    int tau = blockIdx.x * 256 + threadIdx.x;
    if (tau < 32768) {                     // qu[b][he]
        int he = tau >> 6, b = tau & 63;
        const float4* wrow = (const float4*)(Wq + (size_t)he * 1024);
        int u = user_x[b];
        const float4* urow = (const float4*)(upt + (size_t)u * 512);
        float acc = bq[he];
        #pragma unroll 4
        for (int d = 0; d < 128; ++d) {
            float4 w = wrow[d], x = urow[d];
            acc += w.x*x.x + w.y*x.y + w.z*x.z + w.w*x.w;
        }
        ws[OFF_QU + b*512 + he] = acc;
    } else if (tau < 69632) {              // qt / k / v : [t][he]
        int idx = tau - 32768;
        int sec = idx / 12288;             // 0: qt, 1: k, 2: v
        int r   = idx % 12288;
        int he  = r / 24, t = r % 24;      // t fastest -> W row ~wave-uniform
        const float* wbase; float bias; int outoff;
        if (sec == 0)      { wbase = Wq + (size_t)he*1024 + 512; bias = 0.f;    outoff = OFF_QT; }
        else if (sec == 1) { wbase = Wk + (size_t)he*512;        bias = bk[he]; outoff = OFF_K;  }
        else               { wbase = Wv + (size_t)he*512;        bias = bv[he]; outoff = OFF_V;  }
        const float4* w4 = (const float4*)wbase;
        const float4* x4 = (const float4*)(timeslot + t*512);
        float acc = bias;
        #pragma unroll 4
        for (int d = 0; d < 128; ++d) {
            float4 w = w4[d], x = x4[d];
            acc += w.x*x.x + w.y*x.y + w.z*x.z + w.w*x.w;
        }
        ws[outoff + t*512 + he] = acc;
    }
}

// ---------------------------------------------------------------------------
// K2: score tables SU/ST (pre-scaled by 1/sqrt(128)*log2e) and folded
// B matrix Bsw = [VU | VT | zero-pad] in MFMA-B fragment order:
// Bsw[(g*544 + col)*8 + j] = B[k = g*8+j][col], bf16.
// ---------------------------------------------------------------------------
static __device__ __forceinline__ float dot128(const float* __restrict__ a,
                                               const float* __restrict__ b) {
    const float4* a4 = (const float4*)a;
    const float4* b4 = (const float4*)b;
    float acc = 0.f;
    #pragma unroll 8
    for (int i = 0; i < 32; ++i) {
        float4 x = a4[i], y = b4[i];
        acc += x.x*y.x + x.y*y.y + x.z*y.z + x.w*y.w;
    }
    return acc;
}

__global__ __launch_bounds__(256) void k2_small(
    const float* __restrict__ Wu, const float* __restrict__ Wt,
    float* __restrict__ ws)
{
    const float SCL = 1.4426950408889634f / sqrtf(128.0f);  // log2(e) * 1/sqrt(HD)
    int tau = blockIdx.x * 256 + threadIdx.x;
    bf16* Bsw = (bf16*)(ws + OFF_BSW);
    if (tau < 6144) {                       // SU[(b*4+h)*24+kk]
        int kk = tau % 24, h = (tau / 24) & 3, b = tau / 96;
        float acc = dot128(ws + OFF_QU + b*512 + h*128, ws + OFF_K + kk*512 + h*128);
        ws[OFF_SU + tau] = acc * SCL;
    } else if (tau < 8448) {                // ST[(t*4+h)*24+kk]
        int i = tau - 6144;
        int kk = i % 24, h = (i / 24) & 3, t = i / 96;
        float acc = dot128(ws + OFF_QT + t*512 + h*128, ws + OFF_K + kk*512 + h*128);
        ws[OFF_ST + i] = acc * SCL;
    } else if (tau < 57600) {               // VU -> Bsw cols 0..511
        int i = tau - 8448;
        int c = i & 511, r96 = i >> 9;
        int h = r96 / 24, kk = r96 % 24;
        float acc = dot128(ws + OFF_V + kk*512 + h*128, Wu + (size_t)c*512 + h*128);
        Bsw[((r96 >> 3)*544 + c)*8 + (r96 & 7)] = (bf16)acc;
    } else if (tau < 59904) {               // VT -> Bsw cols 512..535
        int i = tau - 57600;
        int j = i % 24, r96 = i / 24;
        int h = r96 / 24, kk = r96 % 24;
        float acc = dot128(ws + OFF_V + kk*512 + h*128, Wt + (size_t)j*512 + h*128);
        Bsw[((r96 >> 3)*544 + 512 + j)*8 + (r96 & 7)] = (bf16)acc;
    } else if (tau < 60672) {               // zero pad cols 536..543
        int i = tau - 59904;
        int g = i >> 6, rem = i & 63;
        int c = 536 + (rem >> 3), j = rem & 7;
        Bsw[(g*544 + c)*8 + j] = (bf16)0.f;
    }
}

// ---------------------------------------------------------------------------
// K3 (main): block = 64 consecutive n (same b). Phase 1: attn -> LDS (bf16,
// A-fragment friendly row-major, row stride 104). Phase 2: MFMA GEMM
// [64 x 96] x [96 x 544] -> bias -> store (cols 0..511 at_emb, 512..535 tl).
// ---------------------------------------------------------------------------
__global__ __launch_bounds__(256) void k3_main(
    const int* __restrict__ hour_x, const int* __restrict__ hour_mask,
    const float* __restrict__ b_unify, const float* __restrict__ b_time,
    const float* __restrict__ ws, float* __restrict__ out)
{
    __shared__ int  maskL[64 * 24];
    __shared__ int  hourL[64];
    __shared__ __align__(16) bf16 attnL[64][104];   // 96 used, pad to 104

    int tid = threadIdx.x;
    int n0  = blockIdx.x * 64;
    int b   = n0 >> 9;

    // stage mask rows (contiguous 6KB region) + hours
    for (int i = tid; i < 64 * 24; i += 256)
        maskL[i] = hour_mask[(size_t)n0 * 24 + i];
    if (tid < 64) hourL[tid] = hour_x[n0 + tid];
    __syncthreads();

    // attention weights: thread = (h, row)
    {
        int h = tid >> 6, row = tid & 63;
        int t = hourL[row];
        const float* su = ws + OFF_SU + (b*4 + h)*24;
        const float* st = ws + OFF_ST + (t*4 + h)*24;
        const int*   m  = maskL + row*24;
        float w[24]; float sum = 0.f;
        #pragma unroll
        for (int kk = 0; kk < 24; ++kk) {
            float e = exp2f(su[kk] + st[kk]);   // exp(score), softmax-shift-free
            e = m[kk] ? 0.f : e;
            w[kk] = e; sum += e;
        }
        float inv = 1.f / sum;                  // k=0 never masked -> sum > 0
        #pragma unroll
        for (int kk = 0; kk < 24; ++kk)
            attnL[row][h*24 + kk] = (bf16)(w[kk] * inv);
    }
    __syncthreads();

    // GEMM phase: wave wv handles rows wv*16..+15, loops 34 col-tiles of 16
    const bf16* Bsw = (const bf16*)(ws + OFF_BSW);
    int wv = tid >> 6, l = tid & 63;
    int quad = l >> 4, cl = l & 15;
    int rowA = wv*16 + cl;

    bf16x8 a0 = *(const bf16x8*)&attnL[rowA][ 0 + quad*8];
    bf16x8 a1 = *(const bf16x8*)&attnL[rowA][32 + quad*8];
    bf16x8 a2 = *(const bf16x8*)&attnL[rowA][64 + quad*8];

    float* tl_out = out + (size_t)NTOT * 512;

    for (int ct = 0; ct < 34; ++ct) {
        int col = ct*16 + cl;
        const bf16* bp = Bsw + ((size_t)(quad*544 + col)) * 8;
        f32x4 acc = {0.f, 0.f, 0.f, 0.f};
        acc = __builtin_amdgcn_mfma_f32_16x16x32_bf16(a0, *(const bf16x8*)(bp),              acc, 0, 0, 0);
        acc = __builtin_amdgcn_mfma_f32_16x16x32_bf16(a1, *(const bf16x8*)(bp + 4*544*8),    acc, 0, 0, 0);
        acc = __builtin_amdgcn_mfma_f32_16x16x32_bf16(a2, *(const bf16x8*)(bp + 8*544*8),    acc, 0, 0, 0);
        int nbase = n0 + wv*16 + quad*4;
        if (col < 512) {
            float bias = b_unify[col];
            #pragma unroll
            for (int r = 0; r < 4; ++r)
                out[(size_t)(nbase + r)*512 + col] = acc[r] + bias;
        } else {
            int cc = col - 512;
            if (cc < 24) {
                float bias = b_time[cc];
                #pragma unroll
                for (int r = 0; r < 4; ++r)
                    tl_out[(size_t)(nbase + r)*24 + cc] = acc[r] + bias;
            }
        }
    }
}

// ---------------------------------------------------------------------------
extern "C" void kernel_launch(void* const* d_in, const int* in_sizes, int n_in,
                              void* d_out, int out_size, void* d_ws, size_t ws_size,
                              hipStream_t stream) {
    const float* timeslot = (const float*)d_in[0];
    // d_in[1] smoothed_timeslot_embedded: unused by reference
    // d_in[2] user_embedded: unused by reference
    const int*   user_x   = (const int*)d_in[3];
    const int*   hour_x   = (const int*)d_in[4];
    const int*   hour_mask= (const int*)d_in[5];
    const float* upt      = (const float*)d_in[6];
    const float* Wq       = (const float*)d_in[7];
    const float* bq       = (const float*)d_in[8];
    const float* Wk       = (const float*)d_in[9];
    const float* bk       = (const float*)d_in[10];
    const float* Wv       = (const float*)d_in[11];
    const float* bv       = (const float*)d_in[12];
    const float* Wu       = (const float*)d_in[13];
    const float* b_unify  = (const float*)d_in[14];
    const float* Wt       = (const float*)d_in[15];
    const float* b_time   = (const float*)d_in[16];

    float* ws  = (float*)d_ws;   // uses ~417 KB of workspace
    float* out = (float*)d_out;

    k1_proj <<<272, 256, 0, stream>>>(timeslot, user_x, upt, Wq, bq, Wk, bk, Wv, bv, ws);
    k2_small<<<237, 256, 0, stream>>>(Wu, Wt, ws);
    k3_main <<<512, 256, 0, stream>>>(hour_x, hour_mask, b_unify, b_time, ws, out);
}

// Round 2
// 344.306 us; speedup vs baseline: 1.0002x; 1.0002x over previous
//
#include <hip/hip_runtime.h>
#include <hip/hip_bf16.h>
#include <math.h>

// Problem constants
#define TS   24
#define NH   4
#define HD   128
#define D    512
#define NB   64
#define SEQ  512
#define NTOT (NB*SEQ)   // 32768

typedef __bf16 bf16;
typedef __bf16 bf16x8 __attribute__((ext_vector_type(8)));
typedef float  f32x4  __attribute__((ext_vector_type(4)));

// Workspace layout (float offsets)
#define OFF_QU  0        // [64][512]   qu[b][h*128+e]  (includes bq)
#define OFF_QT  32768    // [24][512]   qt[t][h*128+e]
#define OFF_K   45056    // [24][512]   k[kk][h*128+e]  (includes bk)
#define OFF_V   57344    // [24][512]   v[kk][h*128+e]  (includes bv)
#define OFF_SU  69632    // [64][4][24] scale*log2e * qu.k
#define OFF_ST  75776    // [24][4][24] scale*log2e * qt.k
#define OFF_BSW 78080    // bf16 region: [12 groups][544 cols][8 k] = 52224 bf16

// ---------------------------------------------------------------------------
// K1: projections. qu (32768 outputs, 512-dots), qt/k/v (3 x 12288, 512-dots).
// qu mapping: lane = b so the Wq row load is wave-uniform; upt rows (64 x 2KB)
// stay hot in L2 across the 512 he-waves.
// ---------------------------------------------------------------------------
__global__ __launch_bounds__(256) void k1_proj(
    const float* __restrict__ timeslot, const int* __restrict__ user_x,
    const float* __restrict__ upt,
    const float* __restrict__ Wq, const float* __restrict__ bq,
    const float* __restrict__ Wk, const float* __restrict__ bk,
    const float* __restrict__ Wv, const float* __restrict__ bv,
    float* __restrict__ ws)
{
    int tau = blockIdx.x * 256 + threadIdx.x;
    if (tau < 32768) {                     // qu[b][he]
        int he = tau >> 6, b = tau & 63;
        const float4* wrow = (const float4*)(Wq + (size_t)he * 1024);
        int u = user_x[b];
        const float4* urow = (const float4*)(upt + (size_t)u * 512);
        float acc = bq[he];
        #pragma unroll 4
        for (int d = 0; d < 128; ++d) {
            float4 w = wrow[d], x = urow[d];
            acc += w.x*x.x + w.y*x.y + w.z*x.z + w.w*x.w;
        }
        ws[OFF_QU + b*512 + he] = acc;
    } else if (tau < 69632) {              // qt / k / v : [t][he]
        int idx = tau - 32768;
        int sec = idx / 12288;             // 0: qt, 1: k, 2: v
        int r   = idx % 12288;
        int he  = r / 24, t = r % 24;      // t fastest -> W row ~wave-uniform
        const float* wbase; float bias; int outoff;
        if (sec == 0)      { wbase = Wq + (size_t)he*1024 + 512; bias = 0.f;    outoff = OFF_QT; }
        else if (sec == 1) { wbase = Wk + (size_t)he*512;        bias = bk[he]; outoff = OFF_K;  }
        else               { wbase = Wv + (size_t)he*512;        bias = bv[he]; outoff = OFF_V;  }
        const float4* w4 = (const float4*)wbase;
        const float4* x4 = (const float4*)(timeslot + t*512);
        float acc = bias;
        #pragma unroll 4
        for (int d = 0; d < 128; ++d) {
            float4 w = w4[d], x = x4[d];
            acc += w.x*x.x + w.y*x.y + w.z*x.z + w.w*x.w;
        }
        ws[outoff + t*512 + he] = acc;
    }
}

// ---------------------------------------------------------------------------
// K2: score tables SU/ST (pre-scaled by 1/sqrt(128)*log2e) and folded
// B matrix Bsw = [VU | VT | zero-pad] in MFMA-B fragment order:
// Bsw[(g*544 + col)*8 + j] = B[k = g*8+j][col], bf16.
// ---------------------------------------------------------------------------
static __device__ __forceinline__ float dot128(const float* __restrict__ a,
                                               const float* __restrict__ b) {
    const float4* a4 = (const float4*)a;
    const float4* b4 = (const float4*)b;
    float acc = 0.f;
    #pragma unroll 8
    for (int i = 0; i < 32; ++i) {
        float4 x = a4[i], y = b4[i];
        acc += x.x*y.x + x.y*y.y + x.z*y.z + x.w*y.w;
    }
    return acc;
}

__global__ __launch_bounds__(256) void k2_small(
    const float* __restrict__ Wu, const float* __restrict__ Wt,
    float* __restrict__ ws)
{
    const float SCL = 1.4426950408889634f / sqrtf(128.0f);  // log2(e) * 1/sqrt(HD)
    int tau = blockIdx.x * 256 + threadIdx.x;
    bf16* Bsw = (bf16*)(ws + OFF_BSW);
    if (tau < 6144) {                       // SU[(b*4+h)*24+kk]
        int kk = tau % 24, h = (tau / 24) & 3, b = tau / 96;
        float acc = dot128(ws + OFF_QU + b*512 + h*128, ws + OFF_K + kk*512 + h*128);
        ws[OFF_SU + tau] = acc * SCL;
    } else if (tau < 8448) {                // ST[(t*4+h)*24+kk]
        int i = tau - 6144;
        int kk = i % 24, h = (i / 24) & 3, t = i / 96;
        float acc = dot128(ws + OFF_QT + t*512 + h*128, ws + OFF_K + kk*512 + h*128);
        ws[OFF_ST + i] = acc * SCL;
    } else if (tau < 57600) {               // VU -> Bsw cols 0..511
        int i = tau - 8448;
        int c = i & 511, r96 = i >> 9;
        int h = r96 / 24, kk = r96 % 24;
        float acc = dot128(ws + OFF_V + kk*512 + h*128, Wu + (size_t)c*512 + h*128);
        Bsw[((r96 >> 3)*544 + c)*8 + (r96 & 7)] = (bf16)acc;
    } else if (tau < 59904) {               // VT -> Bsw cols 512..535
        int i = tau - 57600;
        int j = i % 24, r96 = i / 24;
        int h = r96 / 24, kk = r96 % 24;
        float acc = dot128(ws + OFF_V + kk*512 + h*128, Wt + (size_t)j*512 + h*128);
        Bsw[((r96 >> 3)*544 + 512 + j)*8 + (r96 & 7)] = (bf16)acc;
    } else if (tau < 60672) {               // zero pad cols 536..543
        int i = tau - 59904;
        int g = i >> 6, rem = i & 63;
        int c = 536 + (rem >> 3), j = rem & 7;
        Bsw[(g*544 + c)*8 + j] = (bf16)0.f;
    }
}

// ---------------------------------------------------------------------------
// K3 (main): block = 128 consecutive n (same b, since 128 | 512).
// Phase 1: attn -> LDS (bf16, A-fragment row-major, stride 104).
// Phase 2: MFMA GEMM [128 x 96] x [96 x 544]; each wave owns 2 row-tiles so
// every B-fragment load feeds 2 MFMAs. Col loop split: 32 at_emb tiles then
// 2 time-logit tiles (removes per-iter branch).
// ---------------------------------------------------------------------------
__global__ __launch_bounds__(256) void k3_main(
    const int* __restrict__ hour_x, const int* __restrict__ hour_mask,
    const float* __restrict__ b_unify, const float* __restrict__ b_time,
    const float* __restrict__ ws, float* __restrict__ out)
{
    __shared__ int  maskL[128 * 24];                 // 12 KB
    __shared__ int  hourL[128];
    __shared__ __align__(16) bf16 attnL[128][104];   // 96 used, pad to 104 (26.6 KB)

    int tid = threadIdx.x;
    int n0  = blockIdx.x * 128;
    int b   = n0 >> 9;

    // stage mask rows (contiguous 12KB region, int4) + hours
    {
        const int4* src = (const int4*)(hour_mask + (size_t)n0 * 24);
        int4* dst = (int4*)maskL;
        #pragma unroll
        for (int i = tid; i < 128 * 24 / 4; i += 256)
            dst[i] = src[i];
        if (tid < 128) hourL[tid] = hour_x[n0 + tid];
    }
    __syncthreads();

    // attention weights: 512 tasks (h, row), 2 per thread
    #pragma unroll
    for (int it = 0; it < 2; ++it) {
        int task = tid + it * 256;
        int h = task >> 7, row = task & 127;
        int t = hourL[row];
        const float* su = ws + OFF_SU + (b*4 + h)*24;
        const float* st = ws + OFF_ST + (t*4 + h)*24;
        const int*   m  = maskL + row*24;
        float w[24]; float sum = 0.f;
        #pragma unroll
        for (int kk = 0; kk < 24; ++kk) {
            float e = exp2f(su[kk] + st[kk]);   // exp(score), softmax-shift-free
            e = m[kk] ? 0.f : e;
            w[kk] = e; sum += e;
        }
        float inv = 1.f / sum;                  // k=0 never masked -> sum > 0
        #pragma unroll
        for (int kk = 0; kk < 24; ++kk)
            attnL[row][h*24 + kk] = (bf16)(w[kk] * inv);
    }
    __syncthreads();

    // GEMM phase: wave wv owns rows wv*32..wv*32+31 (2 row-tiles of 16)
    const bf16* Bsw = (const bf16*)(ws + OFF_BSW);
    int wv = tid >> 6, l = tid & 63;
    int quad = l >> 4, cl = l & 15;
    int r0 = wv*32 + cl;          // row-tile 0 A-row
    int r1 = r0 + 16;             // row-tile 1 A-row

    bf16x8 a00 = *(const bf16x8*)&attnL[r0][ 0 + quad*8];
    bf16x8 a01 = *(const bf16x8*)&attnL[r0][32 + quad*8];
    bf16x8 a02 = *(const bf16x8*)&attnL[r0][64 + quad*8];
    bf16x8 a10 = *(const bf16x8*)&attnL[r1][ 0 + quad*8];
    bf16x8 a11 = *(const bf16x8*)&attnL[r1][32 + quad*8];
    bf16x8 a12 = *(const bf16x8*)&attnL[r1][64 + quad*8];

    int nbase = n0 + wv*32 + quad*4;

    // cols 0..511: at_emb
    for (int ct = 0; ct < 32; ++ct) {
        int col = ct*16 + cl;
        const bf16* bp = Bsw + ((size_t)(quad*544 + col)) * 8;
        bf16x8 b0 = *(const bf16x8*)(bp);
        bf16x8 b1 = *(const bf16x8*)(bp + 4*544*8);
        bf16x8 b2 = *(const bf16x8*)(bp + 8*544*8);
        f32x4 acc0 = {0.f, 0.f, 0.f, 0.f};
        f32x4 acc1 = {0.f, 0.f, 0.f, 0.f};
        acc0 = __builtin_amdgcn_mfma_f32_16x16x32_bf16(a00, b0, acc0, 0, 0, 0);
        acc1 = __builtin_amdgcn_mfma_f32_16x16x32_bf16(a10, b0, acc1, 0, 0, 0);
        acc0 = __builtin_amdgcn_mfma_f32_16x16x32_bf16(a01, b1, acc0, 0, 0, 0);
        acc1 = __builtin_amdgcn_mfma_f32_16x16x32_bf16(a11, b1, acc1, 0, 0, 0);
        acc0 = __builtin_amdgcn_mfma_f32_16x16x32_bf16(a02, b2, acc0, 0, 0, 0);
        acc1 = __builtin_amdgcn_mfma_f32_16x16x32_bf16(a12, b2, acc1, 0, 0, 0);
        float bias = b_unify[col];
        #pragma unroll
        for (int r = 0; r < 4; ++r) {
            out[(size_t)(nbase + r)*512 + col]      = acc0[r] + bias;
            out[(size_t)(nbase + 16 + r)*512 + col] = acc1[r] + bias;
        }
    }

    // cols 512..535: time logits (col 536..543 are zero-pad, skipped)
    float* tl_out = out + (size_t)NTOT * 512;
    for (int ct = 32; ct < 34; ++ct) {
        int col = ct*16 + cl;
        int cc  = col - 512;
        const bf16* bp = Bsw + ((size_t)(quad*544 + col)) * 8;
        bf16x8 b0 = *(const bf16x8*)(bp);
        bf16x8 b1 = *(const bf16x8*)(bp + 4*544*8);
        bf16x8 b2 = *(const bf16x8*)(bp + 8*544*8);
        f32x4 acc0 = {0.f, 0.f, 0.f, 0.f};
        f32x4 acc1 = {0.f, 0.f, 0.f, 0.f};
        acc0 = __builtin_amdgcn_mfma_f32_16x16x32_bf16(a00, b0, acc0, 0, 0, 0);
        acc1 = __builtin_amdgcn_mfma_f32_16x16x32_bf16(a10, b0, acc1, 0, 0, 0);
        acc0 = __builtin_amdgcn_mfma_f32_16x16x32_bf16(a01, b1, acc0, 0, 0, 0);
        acc1 = __builtin_amdgcn_mfma_f32_16x16x32_bf16(a11, b1, acc1, 0, 0, 0);
        acc0 = __builtin_amdgcn_mfma_f32_16x16x32_bf16(a02, b2, acc0, 0, 0, 0);
        acc1 = __builtin_amdgcn_mfma_f32_16x16x32_bf16(a12, b2, acc1, 0, 0, 0);
        if (cc < 24) {
            float bias = b_time[cc];
            #pragma unroll
            for (int r = 0; r < 4; ++r) {
                tl_out[(size_t)(nbase + r)*24 + cc]      = acc0[r] + bias;
                tl_out[(size_t)(nbase + 16 + r)*24 + cc] = acc1[r] + bias;
            }
        }
    }
}

// ---------------------------------------------------------------------------
extern "C" void kernel_launch(void* const* d_in, const int* in_sizes, int n_in,
                              void* d_out, int out_size, void* d_ws, size_t ws_size,
                              hipStream_t stream) {
    const float* timeslot = (const float*)d_in[0];
    // d_in[1] smoothed_timeslot_embedded: unused by reference
    // d_in[2] user_embedded: unused by reference
    const int*   user_x   = (const int*)d_in[3];
    const int*   hour_x   = (const int*)d_in[4];
    const int*   hour_mask= (const int*)d_in[5];
    const float* upt      = (const float*)d_in[6];
    const float* Wq       = (const float*)d_in[7];
    const float* bq       = (const float*)d_in[8];
    const float* Wk       = (const float*)d_in[9];
    const float* bk       = (const float*)d_in[10];
    const float* Wv       = (const float*)d_in[11];
    const float* bv       = (const float*)d_in[12];
    const float* Wu       = (const float*)d_in[13];
    const float* b_unify  = (const float*)d_in[14];
    const float* Wt       = (const float*)d_in[15];
    const float* b_time   = (const float*)d_in[16];

    float* ws  = (float*)d_ws;   // uses ~417 KB of workspace
    float* out = (float*)d_out;

    k1_proj <<<272, 256, 0, stream>>>(timeslot, user_x, upt, Wq, bq, Wk, bk, Wv, bv, ws);
    k2_small<<<237, 256, 0, stream>>>(Wu, Wt, ws);
    k3_main <<<256, 256, 0, stream>>>(hour_x, hour_mask, b_unify, b_time, ws, out);
}